// Round 2
// baseline (321.580 us; speedup 1.0000x reference)
//
#include <hip/hip_runtime.h>
#include <hip/hip_bf16.h>
#include <stdint.h>

typedef __bf16 bf16_t;
typedef __bf16 bf16x8 __attribute__((ext_vector_type(8)));
typedef float f32x4 __attribute__((ext_vector_type(4)));
typedef unsigned int u32x4 __attribute__((ext_vector_type(4)));

#define NB 4
#define NH 12
#define ND 64
#define NN 2048
#define NC 768
// M = NB*NN = 8192 rows; qkv cols = 3*NC = 2304

// async global->LDS, 16B per lane; lds dest = wave-uniform base + lane*16
__device__ __forceinline__ void async_copy16(const bf16_t* g, bf16_t* l) {
    __builtin_amdgcn_global_load_lds((__attribute__((address_space(1))) void*)(void*)g,
                                     (__attribute__((address_space(3))) void*)l, 16, 0, 0);
}

__device__ __forceinline__ unsigned pack_bf2(float a, float b) {
    union { bf16_t e[2]; unsigned u; } t;
    t.e[0] = (bf16_t)a;
    t.e[1] = (bf16_t)b;
    return t.u;
}

// ---------------- merged cast fp32 -> bf16 (3 segments), 4 elems/thread ----------------
__global__ void cast3_kernel(const float* __restrict__ s0, bf16_t* __restrict__ d0, int n0,
                             const float* __restrict__ s1, bf16_t* __restrict__ d1, int n1,
                             const float* __restrict__ s2, bf16_t* __restrict__ d2, int n2) {
    int i = blockIdx.x * blockDim.x + threadIdx.x;   // float4 units
    const float* s;
    bf16_t* d;
    int j;
    if (i < n0)           { s = s0; d = d0; j = i; }
    else if (i < n0 + n1) { s = s1; d = d1; j = i - n0; }
    else if (i < n0 + n1 + n2) { s = s2; d = d2; j = i - n0 - n1; }
    else return;
    float4 v = ((const float4*)s)[j];
    union { bf16_t e[4]; uint2 u; } t;
    t.e[0] = (bf16_t)v.x; t.e[1] = (bf16_t)v.y; t.e[2] = (bf16_t)v.z; t.e[3] = (bf16_t)v.w;
    ((uint2*)d)[j] = t.u;
}

// key permutation: key s (within 64-tile) -> V storage position
// pos bits {c5,c4,c3,c2,c1,c0} = {s5, s3, s2, s4, s1, s0}  (s0,s1 fixed -> +p stays consecutive)
// Chosen so that storage slot (hh*4+quad)*8 + t holds exactly the key the PV MFMA's
// k-lane layout expects -> V A-frags are contiguous 16B loads both from LDS and global.
__device__ __forceinline__ int vperm(int s) {
    return (s & 32) | (((s >> 2) & 3) << 3) | (((s >> 4) & 1) << 2) | (s & 3);
}

// GEMM LDS tiles: [rows][8 chunks of 16B], XOR swizzle: data chunk c of row r
// lives at chunk position c ^ (r & 7). Measured conflict-free (SQ_LDS_BANK_CONFLICT=0).

// ---------------- QKV GEMM: [8192,2304] = X[8192,768] @ W[2304,768]^T + b ----------------
// R2 measured-best structure: BK=64 single-buffered, A=X, B=W, one launch, grid (64,18).
// Q,K out bf16 [B,H,N,D] (Q pre-scaled by D^-0.5*log2e); V out bf16 [B,H,D,N], keys
// permuted by vperm within each 64-key tile.
__launch_bounds__(256)
__global__ void qkv_gemm_kernel(const bf16_t* __restrict__ X, const bf16_t* __restrict__ W,
                                const float* __restrict__ bias,
                                bf16_t* __restrict__ Q, bf16_t* __restrict__ K, bf16_t* __restrict__ V)
{
    __shared__ __align__(16) bf16_t sA[128 * 64];
    __shared__ __align__(16) bf16_t sB[128 * 64];
    const int tid  = threadIdx.x;
    const int lane = tid & 63;
    const int w    = tid >> 6;
    const int wm   = w & 1, wn = w >> 1;
    const int m0   = blockIdx.x * 128;
    const int n0   = blockIdx.y * 128;
    const int lrow = lane & 15;
    const int quad = lane >> 4;
    const int arow = lane >> 3;
    const int gch  = (lane & 7) ^ arow;   // swizzled source chunk

    f32x4 zero = {0.f, 0.f, 0.f, 0.f};
    f32x4 acc[4][4];
#pragma unroll
    for (int i = 0; i < 4; ++i)
#pragma unroll
        for (int j = 0; j < 4; ++j) acc[i][j] = zero;

    for (int kt = 0; kt < NC; kt += 64) {
        __syncthreads();
        for (int c = w; c < 16; c += 4) {
            async_copy16(X + (size_t)(m0 + c * 8 + arow) * NC + kt + gch * 8, sA + c * 512);
            async_copy16(W + (size_t)(n0 + c * 8 + arow) * NC + kt + gch * 8, sB + c * 512);
        }
        __syncthreads();
#pragma unroll
        for (int hh = 0; hh < 2; ++hh) {
            bf16x8 af[4], bfr[4];
#pragma unroll
            for (int i = 0; i < 4; ++i) {
                int r = wm * 64 + i * 16 + lrow;
                af[i] = *(const bf16x8*)(sA + r * 64 + (((hh * 4 + quad) ^ (r & 7)) * 8));
            }
#pragma unroll
            for (int j = 0; j < 4; ++j) {
                int r = wn * 64 + j * 16 + lrow;
                bfr[j] = *(const bf16x8*)(sB + r * 64 + (((hh * 4 + quad) ^ (r & 7)) * 8));
            }
#pragma unroll
            for (int i = 0; i < 4; ++i)
#pragma unroll
                for (int j = 0; j < 4; ++j)
                    acc[i][j] = __builtin_amdgcn_mfma_f32_16x16x32_bf16(af[i], bfr[j], acc[i][j], 0, 0, 0);
        }
    }

    const int colbase = n0 + wn * 64;       // 64-aligned -> t3,h uniform per wave
    const int t3 = colbase / NC;
    const int h  = (colbase % NC) / ND;
    const float qscale = 0.125f * 1.44269504088896340736f; // D^-0.5 * log2(e)

#pragma unroll
    for (int j = 0; j < 4; ++j) {
        const int d  = j * 16 + lrow;
        const float bv = bias[colbase + d];
#pragma unroll
        for (int i = 0; i < 4; ++i) {
            const int rowg = m0 + wm * 64 + i * 16 + quad * 4;
            const int bb = rowg >> 11;
            const int nn = rowg & 2047;
            if (t3 == 2) {
                union { bf16_t e[4]; uint2 u; } pk;
#pragma unroll
                for (int p = 0; p < 4; ++p) pk.e[p] = (bf16_t)(acc[i][j][p] + bv);
                const int pos = (nn & ~63) | vperm(nn & 63);
                *(uint2*)(V + ((size_t)(bb * NH + h) * ND + d) * NN + pos) = pk.u;
            } else {
                bf16_t* outb = t3 ? K : Q;
#pragma unroll
                for (int p = 0; p < 4; ++p) {
                    float val = acc[i][j][p] + bv;
                    if (t3 == 0) val *= qscale;
                    outb[((size_t)(bb * NH + h) * NN + nn + p) * ND + d] = (bf16_t)val;
                }
            }
        }
    }
}

// ---------------- flash attention v3: NO LDS, NO barriers, direct-global frags ----------------
// R2 post-mortem: R1 (2-wave) fell with occupancy -> kernel is latency/TLP-bound, not
// LDS-throughput-bound. K/V per head = 256 KB each, re-read by 16 q-blocks -> L2-resident
// (per-XCD working set ~3 MB < 4 MB). So LDS staging = pure overhead (barrier + vmcnt(0)
// drain, 2x per step) per Common-mistake #7. This version loads K/V/Q fragments straight
// from global into registers: zero __shared__, zero __syncthreads, 4 fully independent
// waves/block, 12 waves/CU. V-frag loads are issued before the S MFMAs so their L2 latency
// hides under QK^T+exp2; K latency is covered by 3 waves/SIMD TLP. vperm makes the V
// A-frag a contiguous 16B global load (storage slot (hh*4+quad)*8+t == required key).
// setprio(1) wraps the MFMA clusters (T5; independent drifting waves = m191's +regime).
// Wave w owns q rows [w*32, w*32+32). S^T = K.Q^T: lane holds q = lane&15,
// key = blk*16+quad*4+p. exp2 packed straight into PV B-frags; l via ones-row MFMA.
__launch_bounds__(256, 3)
__global__ void attn_kernel(const bf16_t* __restrict__ Q, const bf16_t* __restrict__ K,
                            const bf16_t* __restrict__ Vt, bf16_t* __restrict__ O)
{
    const int tid  = threadIdx.x;
    const int lane = tid & 63;
    const int w    = tid >> 6;          // 0..3
    const int qt   = blockIdx.x;
    const int h    = blockIdx.y;
    const int b    = blockIdx.z;
    const int lrow = lane & 15;
    const int quad = lane >> 4;
    const size_t head_off = (size_t)(b * NH + h) * NN * ND;
    const bf16_t* qh = Q  + head_off;
    const bf16_t* kh = K  + head_off;
    const bf16_t* vh = Vt + head_off;   // [d][pos], vperm'd within each 64-key tile

    // Q frags direct from global: B-operand rows n = q = w*32+qi*16+lrow, k = hh*32+quad*8..
    bf16x8 qb[2][2];
#pragma unroll
    for (int qi = 0; qi < 2; ++qi)
#pragma unroll
        for (int hh = 0; hh < 2; ++hh)
            qb[qi][hh] = *(const bf16x8*)(qh + (size_t)(qt * 128 + w * 32 + qi * 16 + lrow) * ND
                                             + hh * 32 + quad * 8);

    // ones A-frag for the l row-sum MFMA
    bf16x8 ones;
#pragma unroll
    for (int p = 0; p < 8; ++p) ones[p] = (bf16_t)1.0f;

    f32x4 zero = {0.f, 0.f, 0.f, 0.f};
    f32x4 o[2][4];
#pragma unroll
    for (int qi = 0; qi < 2; ++qi)
#pragma unroll
        for (int db = 0; db < 4; ++db) o[qi][db] = zero;
    f32x4 lacc[2] = {zero, zero};

    // per-lane streaming bases: K frag (blk,hh) at kpl + blk*16*ND + hh*32, step stride 64*ND
    //                           V frag (db,hh)  at vpl + db*16*NN + hh*32, step stride 64
    const bf16_t* kpl = kh + (size_t)lrow * ND + quad * 8;
    const bf16_t* vpl = vh + (size_t)lrow * NN + quad * 8;

    for (int it = 0; it < NN / 64; ++it) {
        // issue all frag loads up front: K first (needed by S), V behind them
        // (V latency hides under S MFMAs + exp2; compiler emits counted vmcnt)
        bf16x8 kf[4][2];
#pragma unroll
        for (int blk = 0; blk < 4; ++blk)
#pragma unroll
            for (int hh = 0; hh < 2; ++hh)
                kf[blk][hh] = *(const bf16x8*)(kpl + blk * 16 * ND + hh * 32);
        bf16x8 vf[4][2];
#pragma unroll
        for (int db = 0; db < 4; ++db)
#pragma unroll
            for (int hh = 0; hh < 2; ++hh)
                vf[db][hh] = *(const bf16x8*)(vpl + db * 16 * NN + hh * 32);
        kpl += (size_t)64 * ND;
        vpl += 64;

        // S^T: A = K rows (m=key), B = Q rows (n=q); frags shared by both strips
        f32x4 s[2][4];
        __builtin_amdgcn_s_setprio(1);
#pragma unroll
        for (int blk = 0; blk < 4; ++blk) {
#pragma unroll
            for (int qi = 0; qi < 2; ++qi) {
                f32x4 z = zero;
                z = __builtin_amdgcn_mfma_f32_16x16x32_bf16(kf[blk][0], qb[qi][0], z, 0, 0, 0);
                z = __builtin_amdgcn_mfma_f32_16x16x32_bf16(kf[blk][1], qb[qi][1], z, 0, 0, 0);
                s[qi][blk] = z;
            }
        }
        __builtin_amdgcn_s_setprio(0);

        // raw v_exp_f32 (scale folded into Q), packed straight into PV B-frags
        bf16x8 pe[2][2];
#pragma unroll
        for (int qi = 0; qi < 2; ++qi) {
            u32x4 pu0 = {0, 0, 0, 0}, pu1 = {0, 0, 0, 0};
#pragma unroll
            for (int blk = 0; blk < 4; ++blk) {
                float e0 = __builtin_amdgcn_exp2f(s[qi][blk][0]);
                float e1 = __builtin_amdgcn_exp2f(s[qi][blk][1]);
                float e2 = __builtin_amdgcn_exp2f(s[qi][blk][2]);
                float e3 = __builtin_amdgcn_exp2f(s[qi][blk][3]);
                unsigned lo = pack_bf2(e0, e1), hi = pack_bf2(e2, e3);
                if (blk == 0)      { pu0[0] = lo; pu0[1] = hi; }
                else if (blk == 1) { pu0[2] = lo; pu0[3] = hi; }
                else if (blk == 2) { pu1[0] = lo; pu1[1] = hi; }
                else               { pu1[2] = lo; pu1[3] = hi; }
            }
            pe[qi][0] = __builtin_bit_cast(bf16x8, pu0);
            pe[qi][1] = __builtin_bit_cast(bf16x8, pu1);
        }

        __builtin_amdgcn_s_setprio(1);
#pragma unroll
        for (int qi = 0; qi < 2; ++qi) {
            // l += row-sum of P via ones-MFMA (all rows of C equal the key-sum)
            lacc[qi] = __builtin_amdgcn_mfma_f32_16x16x32_bf16(ones, pe[qi][0], lacc[qi], 0, 0, 0);
            lacc[qi] = __builtin_amdgcn_mfma_f32_16x16x32_bf16(ones, pe[qi][1], lacc[qi], 0, 0, 0);
        }
        // O^T += V^T . P~ : A = V frags (m=d), B = P~ registers (n=q)
#pragma unroll
        for (int db = 0; db < 4; ++db) {
#pragma unroll
            for (int qi = 0; qi < 2; ++qi) {
                o[qi][db] = __builtin_amdgcn_mfma_f32_16x16x32_bf16(vf[db][0], pe[qi][0], o[qi][db], 0, 0, 0);
                o[qi][db] = __builtin_amdgcn_mfma_f32_16x16x32_bf16(vf[db][1], pe[qi][1], o[qi][db], 0, 0, 0);
            }
        }
        __builtin_amdgcn_s_setprio(0);
    }

    // write attn out bf16 [B,N,C], col = h*64 + d; 4 consecutive d per store
#pragma unroll
    for (int qi = 0; qi < 2; ++qi) {
        const float rl = 1.0f / lacc[qi][0];
        const int n = qt * 128 + w * 32 + qi * 16 + lrow;
        const size_t rowoff = ((size_t)(b * NN + n)) * NC + h * ND;
#pragma unroll
        for (int db = 0; db < 4; ++db) {
            union { bf16_t e[4]; uint2 u; } pk;
#pragma unroll
            for (int p = 0; p < 4; ++p) pk.e[p] = (bf16_t)(o[qi][db][p] * rl);
            *(uint2*)(O + rowoff + db * 16 + quad * 4) = pk.u;
        }
    }
}

// ---------------- proj GEMM: out[8192,768] = A[8192,768] @ W[768,768]^T + b (fp32) ----------------
// R2 measured-best structure: 128x128 tiles, BK=64 single-buffered, non-swapped operands,
// scalar fp32 stores (coalesced across lrow lanes). Grid (64,6).
__launch_bounds__(256)
__global__ void proj_gemm_kernel(const bf16_t* __restrict__ A, const bf16_t* __restrict__ W,
                                 const float* __restrict__ bias, float* __restrict__ out)
{
    __shared__ __align__(16) bf16_t sA[128 * 64];
    __shared__ __align__(16) bf16_t sB[128 * 64];
    const int tid  = threadIdx.x;
    const int lane = tid & 63;
    const int w    = tid >> 6;
    const int wm   = w & 1, wn = w >> 1;
    const int m0   = blockIdx.x * 128;
    const int n0   = blockIdx.y * 128;
    const int lrow = lane & 15;
    const int quad = lane >> 4;
    const int arow = lane >> 3;
    const int gch  = (lane & 7) ^ arow;

    f32x4 zero = {0.f, 0.f, 0.f, 0.f};
    f32x4 acc[4][4];
#pragma unroll
    for (int i = 0; i < 4; ++i)
#pragma unroll
        for (int j = 0; j < 4; ++j) acc[i][j] = zero;

    for (int kt = 0; kt < NC; kt += 64) {
        __syncthreads();
        for (int c = w; c < 16; c += 4) {
            async_copy16(A + (size_t)(m0 + c * 8 + arow) * NC + kt + gch * 8, sA + c * 512);
            async_copy16(W + (size_t)(n0 + c * 8 + arow) * NC + kt + gch * 8, sB + c * 512);
        }
        __syncthreads();
#pragma unroll
        for (int hh = 0; hh < 2; ++hh) {
            bf16x8 af[4], bfr[4];
#pragma unroll
            for (int i = 0; i < 4; ++i) {
                int r = wm * 64 + i * 16 + lrow;
                af[i] = *(const bf16x8*)(sA + r * 64 + (((hh * 4 + quad) ^ (r & 7)) * 8));
            }
#pragma unroll
            for (int j = 0; j < 4; ++j) {
                int r = wn * 64 + j * 16 + lrow;
                bfr[j] = *(const bf16x8*)(sB + r * 64 + (((hh * 4 + quad) ^ (r & 7)) * 8));
            }
#pragma unroll
            for (int i = 0; i < 4; ++i)
#pragma unroll
                for (int j = 0; j < 4; ++j)
                    acc[i][j] = __builtin_amdgcn_mfma_f32_16x16x32_bf16(af[i], bfr[j], acc[i][j], 0, 0, 0);
        }
    }

#pragma unroll
    for (int j = 0; j < 4; ++j) {
        const int colg = n0 + wn * 64 + j * 16 + lrow;
        const float bv = bias[colg];
#pragma unroll
        for (int i = 0; i < 4; ++i) {
            const int rowg = m0 + wm * 64 + i * 16 + quad * 4;
#pragma unroll
            for (int p = 0; p < 4; ++p)
                out[(size_t)(rowg + p) * NC + colg] = acc[i][j][p] + bv;
        }
    }
}

extern "C" void kernel_launch(void* const* d_in, const int* in_sizes, int n_in,
                              void* d_out, int out_size, void* d_ws, size_t ws_size,
                              hipStream_t stream) {
    const float* x      = (const float*)d_in[0];
    const float* qkv_w  = (const float*)d_in[1];
    const float* qkv_b  = (const float*)d_in[2];
    const float* proj_w = (const float*)d_in[3];
    const float* proj_b = (const float*)d_in[4];
    float* out = (float*)d_out;

    char* ws = (char*)d_ws;
    bf16_t* xb    = (bf16_t*)ws; ws += (size_t)8192 * 768 * 2;
    bf16_t* wqkv  = (bf16_t*)ws; ws += (size_t)2304 * 768 * 2;
    bf16_t* wproj = (bf16_t*)ws; ws += (size_t)768 * 768 * 2;
    bf16_t* qb    = (bf16_t*)ws; ws += (size_t)NB * NH * NN * ND * 2;  // [B,H,N,D]
    bf16_t* kb    = (bf16_t*)ws; ws += (size_t)NB * NH * NN * ND * 2;  // [B,H,N,D]
    bf16_t* vb    = (bf16_t*)ws; ws += (size_t)NB * NH * NN * ND * 2;  // [B,H,D,N] permuted
    bf16_t* ab    = (bf16_t*)ws; ws += (size_t)8192 * 768 * 2;         // attn out [B,N,C]

    const int c0 = 8192 * 768 / 4, c1 = 2304 * 768 / 4, c2 = 768 * 768 / 4;
    cast3_kernel<<<(c0 + c1 + c2 + 255) / 256, 256, 0, stream>>>(x, xb, c0, qkv_w, wqkv, c1, proj_w, wproj, c2);

    qkv_gemm_kernel<<<dim3(8192 / 128, 2304 / 128), 256, 0, stream>>>(xb, wqkv, qkv_b, qb, kb, vb);
    attn_kernel<<<dim3(NN / 128, NH, NB), 256, 0, stream>>>(qb, kb, vb, ab);
    proj_gemm_kernel<<<dim3(8192 / 128, 768 / 128), 256, 0, stream>>>(ab, wproj, proj_b, out);
}